// Round 1
// 1366.338 us; speedup vs baseline: 1.2192x; 1.2192x over previous
//
#include <hip/hip_runtime.h>
#include <hip/hip_bf16.h>
#include <math.h>

typedef __hip_bfloat16 bf16;

#define BB    32
#define HH    56
#define WWI   56
#define CC    192
#define NHH   6
#define WSS   7
#define NN    49
#define NWIN  64
#define HDD   32
#define LL    (HH*WWI)
#define ROWS  (BB*NWIN*NN)         // 100352
#define TOT   ((size_t)ROWS*CC)    // 19267584
#define SCALEQ 0.17677669529663687f

// canonical bf16 weight buffer element offsets
#define OFF_N1W   0
#define OFF_N1B   384
#define OFF_QKVW  768
#define OFF_QKVB  221952
#define OFF_RPB   223104
#define OFF_PROJW 225132
#define OFF_PROJB 298860
#define OFF_N2W   299244
#define OFF_N2B   299628
#define OFF_F1W   300012
#define OFF_F1B   594924
#define OFF_F2W   596460
#define OFF_F2B   891372

typedef __bf16 bf16x8v __attribute__((ext_vector_type(8)));
typedef float  f32x4   __attribute__((ext_vector_type(4)));

__device__ __forceinline__ float tof(bf16 v){ return __bfloat162float(v); }
__device__ __forceinline__ bf16  tob(float v){ return __float2bfloat16(v); }
__device__ __forceinline__ float xload(const float* p){ return *p; }
__device__ __forceinline__ float xload(const bf16*  p){ return tof(*p); }
__device__ __forceinline__ void  xstore(float* p, float v){ *p = v; }
__device__ __forceinline__ void  xstore(bf16*  p, float v){ *p = tob(v); }

__device__ __forceinline__ bf16x8v ldfrag(const bf16* p){
    return *(const bf16x8v*)p;
}
__device__ __forceinline__ unsigned short bfbits(float v){
    bf16 b = tob(v);
    return __builtin_bit_cast(unsigned short, b);
}
__device__ __forceinline__ bf16 mkbf(unsigned short u){
    return __builtin_bit_cast(bf16, u);
}

// ---------- dtype detect ----------
__global__ void k_detect(const unsigned short* __restrict__ w, int* __restrict__ flag){
    if (blockIdx.x == 0 && threadIdx.x == 0){
        int cnt = 0;
        for (int k = 0; k < 16; ++k){
            unsigned short u = w[2*k];
            if (u >= 0x3E00 && u <= 0x4100) ++cnt;
        }
        *flag = (cnt >= 8) ? 1 : 0;
    }
}

__global__ void k_canon(const void* __restrict__ src, bf16* __restrict__ dst,
                        int n, const int* __restrict__ flag){
    int i = blockIdx.x * blockDim.x + threadIdx.x;
    if (i >= n) return;
    if (*flag) dst[i] = ((const bf16*)src)[i];
    else       dst[i] = tob(((const float*)src)[i]);
}

template<typename XT>
__global__ void k_convert_in(const void* __restrict__ in, XT* __restrict__ X,
                             const int* __restrict__ flag){
    size_t i = (size_t)blockIdx.x * blockDim.x + threadIdx.x;
    if (i >= TOT) return;
    float v = (*flag) ? tof(((const bf16*)in)[i]) : ((const float*)in)[i];
    xstore(&X[i], v);
}

template<typename XT>
__global__ void k_out(const XT* __restrict__ X, void* __restrict__ out,
                      const int* __restrict__ flag){
    size_t i = (size_t)blockIdx.x * blockDim.x + threadIdx.x;
    if (i >= TOT) return;
    float v = xload(&X[i]);
    if (*flag) ((bf16*)out)[i] = tob(v);
    else       ((float*)out)[i] = v;
}

// ---------- LN1 + shift + window partition ----------
template<typename XT>
__global__ void k_ln_part(const XT* __restrict__ X, const bf16* __restrict__ w,
                          const bf16* __restrict__ bsh, bf16* __restrict__ Hwin,
                          int shift){
    __shared__ float red[CC], red2[CC], stats[2];
    int row = blockIdx.x;
    int t = threadIdx.x;
    int b   = row / (NWIN*NN);
    int win = (row / NN) % NWIN;
    int n   = row % NN;
    int wh = win >> 3, ww = win & 7;
    int iy = n / WSS, ix = n % WSS;
    int sy = (wh*WSS + iy + shift) % HH;
    int sx = (ww*WSS + ix + shift) % WWI;
    const XT* src = X + ((size_t)(b*LL + sy*WWI + sx))*CC;
    float v = xload(&src[t]);
    red[t] = v; red2[t] = v*v;
    __syncthreads();
    for (int off = 96; off >= 3; off >>= 1){
        if (t < off){ red[t] += red[t+off]; red2[t] += red2[t+off]; }
        __syncthreads();
    }
    if (t == 0){
        float su  = red[0] + red[1] + red[2];
        float su2 = red2[0] + red2[1] + red2[2];
        float mu  = su * (1.f/CC);
        float var = su2 * (1.f/CC) - mu*mu;
        stats[0] = mu;
        stats[1] = rsqrtf(var + 1e-5f);
    }
    __syncthreads();
    float o = (v - stats[0]) * stats[1] * tof(w[t]) + tof(bsh[t]);
    Hwin[(size_t)row*CC + t] = tob(o);
}

// ---------- window attention, MFMA, 4-barrier structure ----------
// one block (512 thr, 8 waves) per window. M tile starts {0,16,32,33}.
__device__ __forceinline__ int mt0(int i){ return (i < 3) ? i*16 : 33; }

// LDS layout (elements, bf16):
//   qls : [0      .. 9407 ]  49 x 192, swizzled  (q, pre-scaled)
//   kls : [9408   .. 18815]  49 x 192, swizzled
//   vT  : [18816  .. 31103]  192 x 64, swizzled  (tok-major transposed V)
//   Pls : aliases qls+kls    (6*49) x 64, swizzled (probabilities)
// swizzle: element col ^ ((row&7)<<3)  — keeps 8-elem (16B) chunks aligned,
// makes stride-192/stride-64 ds_read_b128 bank-even.
__global__ __launch_bounds__(512, 4) void k_attn(const bf16* __restrict__ Hwin,
        const bf16* __restrict__ qkvw, const bf16* __restrict__ qkvb,
        const bf16* __restrict__ rpb, bf16* __restrict__ AOut, int masked){
    __shared__ bf16 smem[31104];                 // 62208 B
    bf16* qls = smem;
    bf16* kls = smem + 9408;
    bf16* vT  = smem + 18816;
    bf16* Pls = smem;                            // alias q+k after barrier #2

    int t = threadIdx.x;
    int win  = blockIdx.x;
    int winl = win & (NWIN-1);
    int wh = winl >> 3, ww = winl & 7;
    int wv = t >> 6, lane = t & 63;
    int li16 = lane & 15, quad = lane >> 4;

    // zero vT pad cols (toks 49..63) once; covered by barrier #1
    for (int idx = t; idx < 192*15; idx += 512){
        int d = idx / 15, tokp = 49 + idx % 15;
        vT[d*64 + (tokp ^ ((d&7)<<3))] = tob(0.f);
    }

    // ---- phase Q: QKV for ALL heads, one long phase ----
    {
        int p = wv & 1, c = wv >> 1;             // mt-pair, nt residue class
        int m0a = mt0(2*p), m0b = mt0(2*p+1);
        const bf16* hg = Hwin + (size_t)win*NN*CC;
        bf16x8v afa[6], afb[6];
        #pragma unroll
        for (int kc = 0; kc < 6; ++kc){
            afa[kc] = ldfrag(hg + (m0a+li16)*CC + kc*32 + quad*8);
            afb[kc] = ldfrag(hg + (m0b+li16)*CC + kc*32 + quad*8);
        }
        #pragma unroll 3
        for (int j = 0; j < 9; ++j){
            int nt = c + 4*j;                    // 0..35
            int col = nt*16 + li16;              // 0..575
            f32x4 acc0 = {0.f,0.f,0.f,0.f}, acc1 = {0.f,0.f,0.f,0.f};
            #pragma unroll
            for (int kc = 0; kc < 6; ++kc){
                bf16x8v bfr = ldfrag(qkvw + (size_t)col*CC + kc*32 + quad*8);
                acc0 = __builtin_amdgcn_mfma_f32_16x16x32_bf16(afa[kc], bfr, acc0, 0, 0, 0);
                acc1 = __builtin_amdgcn_mfma_f32_16x16x32_bf16(afb[kc], bfr, acc1, 0, 0, 0);
            }
            float bias = tof(qkvb[col]);
            int m  = col / CC;                   // 0=q 1=k 2=v (wave-uniform)
            int cm = col - m*CC;                 // h*32+dl
            #pragma unroll
            for (int r = 0; r < 4; ++r){
                int rowA = m0a + quad*4 + r;
                int rowB = m0b + quad*4 + r;
                float v0 = acc0[r] + bias, v1 = acc1[r] + bias;
                if (m == 0){
                    qls[rowA*CC + (cm ^ ((rowA&7)<<3))] = tob(v0*SCALEQ);
                    qls[rowB*CC + (cm ^ ((rowB&7)<<3))] = tob(v1*SCALEQ);
                } else if (m == 1){
                    kls[rowA*CC + (cm ^ ((rowA&7)<<3))] = tob(v0);
                    kls[rowB*CC + (cm ^ ((rowB&7)<<3))] = tob(v1);
                } else {
                    vT[cm*64 + (rowA ^ ((cm&7)<<3))] = tob(v0);
                    vT[cm*64 + (rowB ^ ((cm&7)<<3))] = tob(v1);
                }
            }
        }
    }
    __syncthreads();   // #1: q,k,vT visible

    // ---- phase S: scores + bias + mask + in-register softmax ----
    // 24 tasks (mt,h), 3 per wave; lane holds S[m0+quad*4+r][nt*16+li16]
    unsigned int pk[3][8];
    #pragma unroll
    for (int j = 0; j < 3; ++j){
        int id = wv + 8*j;                       // 0..23
        int mt = id & 3, h = id >> 2;
        int m0 = mt0(mt);
        int rowq = m0 + li16;
        bf16x8v afr = ldfrag(qls + rowq*CC + ((h*32 + quad*8) ^ ((rowq&7)<<3)));
        f32x4 s[4];
        #pragma unroll
        for (int nt = 0; nt < 4; ++nt){
            int rowk = nt*16 + li16;             // nt=3,li16>0 reads junk; masked below
            bf16x8v bfr = ldfrag(kls + rowk*CC + ((h*32 + quad*8) ^ ((rowk&7)<<3)));
            f32x4 z = {0.f,0.f,0.f,0.f};
            s[nt] = __builtin_amdgcn_mfma_f32_16x16x32_bf16(afr, bfr, z, 0, 0, 0);
        }
        #pragma unroll
        for (int nt = 0; nt < 4; ++nt){
            int jj = nt*16 + li16;
            int valid = (jj < NN);
            int jc = valid ? jj : 48;
            int yj = (jc*37) >> 8, xj = jc - 7*yj;
            int lj = 0;
            if (masked){
                int ayj = wh*WSS + yj, axj = ww*WSS + xj;
                lj = ((ayj<49)?0:(ayj<53)?1:2)*3 + ((axj<49)?0:(axj<53)?1:2);
            }
            #pragma unroll
            for (int r = 0; r < 4; ++r){
                int i = m0 + quad*4 + r;
                int yi = (i*37) >> 8, xi = i - 7*yi;
                int ridx = (yi - yj + 6)*13 + (xi - xj + 6);
                float v = s[nt][r] + tof(rpb[ridx*NHH + h]);
                if (masked){
                    int ayi = wh*WSS + yi, axi = ww*WSS + xi;
                    int li = ((ayi<49)?0:(ayi<53)?1:2)*3 + ((axi<49)?0:(axi<53)?1:2);
                    if (li != lj) v -= 100.f;
                }
                s[nt][r] = valid ? v : -1e30f;
            }
        }
        // row max (cols live in li16 lanes of same quad + 4 in-lane nts)
        float mx[4], sm[4];
        #pragma unroll
        for (int r = 0; r < 4; ++r)
            mx[r] = fmaxf(fmaxf(s[0][r], s[1][r]), fmaxf(s[2][r], s[3][r]));
        #pragma unroll
        for (int st = 1; st < 16; st <<= 1){
            #pragma unroll
            for (int r = 0; r < 4; ++r) mx[r] = fmaxf(mx[r], __shfl_xor(mx[r], st));
        }
        #pragma unroll
        for (int nt = 0; nt < 4; ++nt){
            #pragma unroll
            for (int r = 0; r < 4; ++r) s[nt][r] = __expf(s[nt][r] - mx[r]);
        }
        #pragma unroll
        for (int r = 0; r < 4; ++r) sm[r] = (s[0][r]+s[1][r]) + (s[2][r]+s[3][r]);
        #pragma unroll
        for (int st = 1; st < 16; st <<= 1){
            #pragma unroll
            for (int r = 0; r < 4; ++r) sm[r] += __shfl_xor(sm[r], st);
        }
        #pragma unroll
        for (int r = 0; r < 4; ++r) sm[r] = 1.f / sm[r];
        // pack P to bf16 pairs (held across barrier)
        #pragma unroll
        for (int nt = 0; nt < 4; ++nt){
            #pragma unroll
            for (int rr = 0; rr < 2; ++rr){
                unsigned int u0 = bfbits(s[nt][2*rr]   * sm[2*rr]);
                unsigned int u1 = bfbits(s[nt][2*rr+1] * sm[2*rr+1]);
                pk[j][nt*2+rr] = (u1 << 16) | u0;
            }
        }
    }
    __syncthreads();  // #2: all q/k reads done -> safe to overwrite with P

    #pragma unroll
    for (int j = 0; j < 3; ++j){
        int id = wv + 8*j;
        int m0 = mt0(id & 3), h = id >> 2;
        #pragma unroll
        for (int nt = 0; nt < 4; ++nt){
            int jj = nt*16 + li16;               // cols >=49 carry exact 0
            #pragma unroll
            for (int rr = 0; rr < 2; ++rr){
                unsigned int u = pk[j][nt*2+rr];
                int tok0 = m0 + quad*4 + 2*rr;
                int tok1 = tok0 + 1;
                Pls[(h*NN + tok0)*64 + (jj ^ ((tok0&7)<<3))] = mkbf((unsigned short)(u & 0xffff));
                Pls[(h*NN + tok1)*64 + (jj ^ ((tok1&7)<<3))] = mkbf((unsigned short)(u >> 16));
            }
        }
    }
    __syncthreads();  // #3: P visible

    // ---- phase PV: O = P V, all heads; 48 tiles, 6 per wave ----
    {
        int mt = wv & 3, nto = wv >> 2;
        int m0 = mt0(mt), n0 = nto*16;
        #pragma unroll
        for (int h = 0; h < NHH; ++h){
            f32x4 acc = {0.f,0.f,0.f,0.f};
            #pragma unroll
            for (int kc = 0; kc < 2; ++kc){
                int rowp = m0 + li16;
                bf16x8v afr = ldfrag(Pls + (h*NN + rowp)*64 + ((kc*32 + quad*8) ^ ((rowp&7)<<3)));
                int rowv = h*HDD + n0 + li16;
                bf16x8v bfr = ldfrag(vT + rowv*64 + ((kc*32 + quad*8) ^ ((rowv&7)<<3)));
                acc = __builtin_amdgcn_mfma_f32_16x16x32_bf16(afr, bfr, acc, 0, 0, 0);
            }
            #pragma unroll
            for (int r = 0; r < 4; ++r){
                int tok = m0 + quad*4 + r;
                AOut[(size_t)win*NN*CC + tok*CC + h*HDD + n0 + li16] = tob(acc[r]);
            }
        }
    }
}

// ---------- proj (MFMA) + window reverse + roll-by-WS bug + residual ----------
#define AS_STRIDE 200
template<typename XT>
__global__ __launch_bounds__(256) void k_proj_res(const bf16* __restrict__ AOut,
        const bf16* __restrict__ pw, const bf16* __restrict__ pb,
        XT* __restrict__ X, int shift){
    __shared__ bf16 as[32*AS_STRIDE];
    int t = threadIdx.x;
    int row0 = blockIdx.x * 32;
    for (int idx = t; idx < 32*CC; idx += 256){
        int r = idx / CC, c = idx % CC;
        as[r*AS_STRIDE + c] = AOut[(size_t)(row0 + r)*CC + c];
    }
    __syncthreads();
    int wv = t >> 6, lane = t & 63;
    int li16 = lane & 15, quad = lane >> 4;
    int roll = (shift > 0) ? WSS : 0;
    for (int nt = 0; nt < 3; ++nt){
        int n0 = wv*48 + nt*16;
        int col = n0 + li16;
        bf16x8v bfr[6];
        #pragma unroll
        for (int kc = 0; kc < 6; ++kc)
            bfr[kc] = ldfrag(pw + (size_t)col*CC + kc*32 + quad*8);
        float bias = tof(pb[col]);
        for (int mt = 0; mt < 2; ++mt){
            int m0 = mt*16;
            f32x4 acc = {0.f,0.f,0.f,0.f};
            #pragma unroll
            for (int kc = 0; kc < 6; ++kc){
                bf16x8v afr = ldfrag(as + (m0 + li16)*AS_STRIDE + kc*32 + quad*8);
                acc = __builtin_amdgcn_mfma_f32_16x16x32_bf16(afr, bfr[kc], acc, 0, 0, 0);
            }
            #pragma unroll
            for (int r = 0; r < 4; ++r){
                int grow = row0 + m0 + quad*4 + r;
                int b   = grow / (NWIN*NN);
                int rem = grow % (NWIN*NN);
                int win = rem / NN;
                int n   = rem % NN;
                int wh = win >> 3, ww = win & 7;
                int iy = n / WSS, ix = n % WSS;
                int y = (wh*WSS + iy + roll) % HH;
                int x = (ww*WSS + ix + roll) % WWI;
                size_t idx = ((size_t)(b*LL + y*WWI + x))*CC + col;
                xstore(&X[idx], xload(&X[idx]) + acc[r] + bias);
            }
        }
    }
}

// ---------- LN2 + FC1(MFMA) + GELU + FC2(MFMA) + residual ----------
#define H1_STRIDE 776
template<typename XT>
__global__ __launch_bounds__(256) void k_mlp(XT* __restrict__ X,
        const bf16* __restrict__ n2w, const bf16* __restrict__ n2b,
        const bf16* __restrict__ w1, const bf16* __restrict__ b1,
        const bf16* __restrict__ w2, const bf16* __restrict__ b2){
    __shared__ bf16  xin[32*AS_STRIDE];
    __shared__ bf16  h1[32*H1_STRIDE];
    __shared__ float part[256], part2[256];
    __shared__ float stats[64];
    int t = threadIdx.x;
    size_t row0 = (size_t)blockIdx.x * 32;
    {
        int r = t >> 3, s = t & 7;
        const XT* xr = X + (row0 + r)*CC + s*24;
        float sm = 0.f, sm2 = 0.f;
        #pragma unroll
        for (int c = 0; c < 24; ++c){ float v = xload(&xr[c]); sm += v; sm2 += v*v; }
        part[t] = sm; part2[t] = sm2;
    }
    __syncthreads();
    if (t < 32){
        float s = 0.f, s2 = 0.f;
        #pragma unroll
        for (int k = 0; k < 8; ++k){ s += part[t*8+k]; s2 += part2[t*8+k]; }
        float mu  = s * (1.f/CC);
        float var = s2 * (1.f/CC) - mu*mu;
        stats[t]      = mu;
        stats[32 + t] = rsqrtf(var + 1e-5f);
    }
    __syncthreads();
    for (int idx = t; idx < 32*CC; idx += 256){
        int r = idx / CC, c = idx % CC;
        float v = xload(&X[(row0 + r)*CC + c]);
        xin[r*AS_STRIDE + c] = tob((v - stats[r]) * stats[32+r] * tof(n2w[c]) + tof(n2b[c]));
    }
    __syncthreads();
    int wv = t >> 6, lane = t & 63;
    int li16 = lane & 15, quad = lane >> 4;
    for (int nt = 0; nt < 12; ++nt){
        int n0 = wv*192 + nt*16;
        int col = n0 + li16;
        bf16x8v bfr[6];
        #pragma unroll
        for (int kc = 0; kc < 6; ++kc)
            bfr[kc] = ldfrag(w1 + (size_t)col*CC + kc*32 + quad*8);
        float bb = tof(b1[col]);
        for (int mt = 0; mt < 2; ++mt){
            int m0 = mt*16;
            f32x4 acc = {0.f,0.f,0.f,0.f};
            #pragma unroll
            for (int kc = 0; kc < 6; ++kc){
                bf16x8v afr = ldfrag(xin + (m0 + li16)*AS_STRIDE + kc*32 + quad*8);
                acc = __builtin_amdgcn_mfma_f32_16x16x32_bf16(afr, bfr[kc], acc, 0, 0, 0);
            }
            #pragma unroll
            for (int r = 0; r < 4; ++r){
                int mrow = m0 + quad*4 + r;
                float xv = acc[r] + bb;
                float g  = 0.5f*xv*(1.f + erff(xv*0.70710678118f));
                h1[mrow*H1_STRIDE + col] = tob(g);
            }
        }
    }
    __syncthreads();
    for (int nt = 0; nt < 3; ++nt){
        int n0 = wv*48 + nt*16;
        int col = n0 + li16;
        f32x4 acc0 = {0.f,0.f,0.f,0.f};
        f32x4 acc1 = {0.f,0.f,0.f,0.f};
        for (int kc = 0; kc < 24; ++kc){
            bf16x8v bfr = ldfrag(w2 + (size_t)col*768 + kc*32 + quad*8);
            bf16x8v a0  = ldfrag(h1 + (0  + li16)*H1_STRIDE + kc*32 + quad*8);
            bf16x8v a1  = ldfrag(h1 + (16 + li16)*H1_STRIDE + kc*32 + quad*8);
            acc0 = __builtin_amdgcn_mfma_f32_16x16x32_bf16(a0, bfr, acc0, 0, 0, 0);
            acc1 = __builtin_amdgcn_mfma_f32_16x16x32_bf16(a1, bfr, acc1, 0, 0, 0);
        }
        float bias = tof(b2[col]);
        #pragma unroll
        for (int r = 0; r < 4; ++r){
            size_t i0 = (row0 + 0  + quad*4 + r)*CC + col;
            size_t i1 = (row0 + 16 + quad*4 + r)*CC + col;
            xstore(&X[i0], xload(&X[i0]) + acc0[r] + bias);
            xstore(&X[i1], xload(&X[i1]) + acc1[r] + bias);
        }
    }
}

// ---------- driver ----------
template<typename XT>
static void run_pipeline(const bf16* wb, const void* xin, int* flag,
                         XT* X, bf16* Hwin, bf16* AOut, void* out,
                         hipStream_t stream){
    k_convert_in<XT><<<(int)(TOT/256), 256, 0, stream>>>(xin, X, flag);
    for (int i = 0; i < 2; ++i){
        int shift = i ? (WSS/2) : 0;
        k_ln_part<XT><<<ROWS, CC, 0, stream>>>(X, wb+OFF_N1W + i*CC,
                wb+OFF_N1B + i*CC, Hwin, shift);
        k_attn<<<BB*NWIN, 512, 0, stream>>>(Hwin,
                wb+OFF_QKVW + (size_t)i*3*CC*CC, wb+OFF_QKVB + (size_t)i*3*CC,
                wb+OFF_RPB + (size_t)i*169*NHH, AOut, i);
        k_proj_res<XT><<<ROWS/32, 256, 0, stream>>>(AOut,
                wb+OFF_PROJW + (size_t)i*CC*CC, wb+OFF_PROJB + i*CC, X, shift);
        k_mlp<XT><<<ROWS/32, 256, 0, stream>>>(X,
                wb+OFF_N2W + i*CC, wb+OFF_N2B + i*CC,
                wb+OFF_F1W + (size_t)i*4*CC*CC, wb+OFF_F1B + (size_t)i*4*CC,
                wb+OFF_F2W + (size_t)i*CC*4*CC, wb+OFF_F2B + i*CC);
    }
    k_out<XT><<<(int)(TOT/256), 256, 0, stream>>>(X, out, flag);
}

extern "C" void kernel_launch(void* const* d_in, const int* in_sizes, int n_in,
                              void* d_out, int out_size, void* d_ws, size_t ws_size,
                              hipStream_t stream){
    char* p = (char*)d_ws;
    int*  flag = (int*)p;
    bf16* wb   = (bf16*)(p + 16);
    char* q    = p + 16 + (2u<<20);

    k_detect<<<1, 64, 0, stream>>>((const unsigned short*)d_in[1], flag);

    static const int widx[13] = {1,2,3,4,5,6,7,8,9,10,11,12,13};
    static const int woff[13] = {OFF_N1W,OFF_N1B,OFF_QKVW,OFF_QKVB,OFF_RPB,
                                 OFF_PROJW,OFF_PROJB,OFF_N2W,OFF_N2B,
                                 OFF_F1W,OFF_F1B,OFF_F2W,OFF_F2B};
    static const int wsz[13]  = {384,384,221184,1152,2028,73728,384,384,384,
                                 294912,1536,294912,384};
    for (int k = 0; k < 13; ++k)
        k_canon<<<(wsz[k]+255)/256, 256, 0, stream>>>(d_in[widx[k]], wb+woff[k],
                                                      wsz[k], flag);

    size_t needF32 = 16 + (2u<<20) + TOT*4 + TOT*2 + TOT*2;
    if (ws_size >= needF32){
        float* X   = (float*)q;       q += TOT*4;
        bf16* Hwin = (bf16*)q;        q += TOT*2;
        bf16* AOut = (bf16*)q;
        run_pipeline<float>(wb, d_in[0], flag, X, Hwin, AOut, d_out, stream);
    } else {
        bf16* X    = (bf16*)q;        q += TOT*2;
        bf16* Hwin = (bf16*)q;        q += TOT*2;
        bf16* AOut = (bf16*)q;
        run_pipeline<bf16>(wb, d_in[0], flag, X, Hwin, AOut, d_out, stream);
    }
}

// Round 2
// 1202.484 us; speedup vs baseline: 1.3853x; 1.1363x over previous
//
#include <hip/hip_runtime.h>
#include <hip/hip_bf16.h>
#include <math.h>

typedef __hip_bfloat16 bf16;

#define BB    32
#define HH    56
#define WWI   56
#define CC    192
#define NHH   6
#define WSS   7
#define NN    49
#define NWIN  64
#define HDD   32
#define LL    (HH*WWI)
#define ROWS  (BB*NWIN*NN)         // 100352
#define TOT   ((size_t)ROWS*CC)    // 19267584
#define SCALEQ 0.17677669529663687f

// canonical bf16 weight buffer element offsets
#define OFF_N1W   0
#define OFF_N1B   384
#define OFF_QKVW  768
#define OFF_QKVB  221952
#define OFF_RPB   223104
#define OFF_PROJW 225132
#define OFF_PROJB 298860
#define OFF_N2W   299244
#define OFF_N2B   299628
#define OFF_F1W   300012
#define OFF_F1B   594924
#define OFF_F2W   596460
#define OFF_F2B   891372

typedef __bf16 bf16x8v __attribute__((ext_vector_type(8)));
typedef float  f32x4   __attribute__((ext_vector_type(4)));

__device__ __forceinline__ float tof(bf16 v){ return __bfloat162float(v); }
__device__ __forceinline__ bf16  tob(float v){ return __float2bfloat16(v); }
__device__ __forceinline__ float xload(const float* p){ return *p; }
__device__ __forceinline__ float xload(const bf16*  p){ return tof(*p); }
__device__ __forceinline__ void  xstore(float* p, float v){ *p = v; }
__device__ __forceinline__ void  xstore(bf16*  p, float v){ *p = tob(v); }

__device__ __forceinline__ bf16x8v ldfrag(const bf16* p){
    return *(const bf16x8v*)p;
}
__device__ __forceinline__ unsigned short bfbits(float v){
    bf16 b = tob(v);
    return __builtin_bit_cast(unsigned short, b);
}
__device__ __forceinline__ bf16 mkbf(unsigned short u){
    return __builtin_bit_cast(bf16, u);
}

// A&S 7.1.26 erf, |eps| <= 1.5e-7; gelu exact form
__device__ __forceinline__ float fast_gelu(float x){
    float u = fabsf(x) * 0.70710678118f;
    float t = __builtin_amdgcn_rcpf(1.f + 0.3275911f*u);
    float p = t*(0.254829592f + t*(-0.284496736f + t*(1.421413741f +
              t*(-1.453152027f + t*1.061405429f))));
    float e = __expf(-u*u);
    float erfu = 1.f - p*e;
    float s = copysignf(erfu, x);
    return 0.5f*x*(1.f + s);
}

// ---------- dtype detect ----------
__global__ void k_detect(const unsigned short* __restrict__ w, int* __restrict__ flag){
    if (blockIdx.x == 0 && threadIdx.x == 0){
        int cnt = 0;
        for (int k = 0; k < 16; ++k){
            unsigned short u = w[2*k];
            if (u >= 0x3E00 && u <= 0x4100) ++cnt;
        }
        *flag = (cnt >= 8) ? 1 : 0;
    }
}

__global__ void k_canon(const void* __restrict__ src, bf16* __restrict__ dst,
                        int n, const int* __restrict__ flag){
    int i = blockIdx.x * blockDim.x + threadIdx.x;
    if (i >= n) return;
    if (*flag) dst[i] = ((const bf16*)src)[i];
    else       dst[i] = tob(((const float*)src)[i]);
}

template<typename XT>
__global__ void k_convert_in(const void* __restrict__ in, XT* __restrict__ X,
                             const int* __restrict__ flag){
    size_t i = (size_t)blockIdx.x * blockDim.x + threadIdx.x;
    if (i >= TOT) return;
    float v = (*flag) ? tof(((const bf16*)in)[i]) : ((const float*)in)[i];
    xstore(&X[i], v);
}

template<typename XT>
__global__ void k_out(const XT* __restrict__ X, void* __restrict__ out,
                      const int* __restrict__ flag){
    size_t i = (size_t)blockIdx.x * blockDim.x + threadIdx.x;
    if (i >= TOT) return;
    float v = xload(&X[i]);
    if (*flag) ((bf16*)out)[i] = tob(v);
    else       ((float*)out)[i] = v;
}

// ---------- LN1 + shift + window partition : wave-per-row, no LDS ----------
template<typename XT>
__global__ __launch_bounds__(256) void k_ln_part(const XT* __restrict__ X,
        const bf16* __restrict__ w, const bf16* __restrict__ bsh,
        bf16* __restrict__ Hwin, int shift){
    int wv = threadIdx.x >> 6, lane = threadIdx.x & 63;
    int row = blockIdx.x*4 + wv;                 // ROWS % 4 == 0
    int b   = row / (NWIN*NN);
    int win = (row / NN) % NWIN;
    int n   = row % NN;
    int wh = win >> 3, ww = win & 7;
    int iy = n / WSS, ix = n % WSS;
    int sy = (wh*WSS + iy + shift) % HH;
    int sx = (ww*WSS + ix + shift) % WWI;
    const XT* src = X + ((size_t)(b*LL + sy*WWI + sx))*CC;
    float v0 = xload(&src[lane]);
    float v1 = xload(&src[lane+64]);
    float v2 = xload(&src[lane+128]);
    float sm  = v0+v1+v2;
    float sm2 = v0*v0+v1*v1+v2*v2;
    #pragma unroll
    for (int st = 1; st < 64; st <<= 1){
        sm  += __shfl_xor(sm,  st);
        sm2 += __shfl_xor(sm2, st);
    }
    float mu  = sm * (1.f/CC);
    float inv = rsqrtf(sm2*(1.f/CC) - mu*mu + 1e-5f);
    bf16* dst = Hwin + (size_t)row*CC;
    dst[lane]     = tob((v0-mu)*inv*tof(w[lane])     + tof(bsh[lane]));
    dst[lane+64]  = tob((v1-mu)*inv*tof(w[lane+64])  + tof(bsh[lane+64]));
    dst[lane+128] = tob((v2-mu)*inv*tof(w[lane+128]) + tof(bsh[lane+128]));
}

// ---------- window attention, MFMA, 4-barrier structure ----------
__device__ __forceinline__ int mt0(int i){ return (i < 3) ? i*16 : 33; }

__global__ __launch_bounds__(512, 4) void k_attn(const bf16* __restrict__ Hwin,
        const bf16* __restrict__ qkvw, const bf16* __restrict__ qkvb,
        const bf16* __restrict__ rpb, bf16* __restrict__ AOut, int masked){
    __shared__ bf16 smem[31104];                 // 62208 B
    bf16* qls = smem;
    bf16* kls = smem + 9408;
    bf16* vT  = smem + 18816;
    bf16* Pls = smem;                            // alias q+k after barrier #2

    int t = threadIdx.x;
    int win  = blockIdx.x;
    int winl = win & (NWIN-1);
    int wh = winl >> 3, ww = winl & 7;
    int wv = t >> 6, lane = t & 63;
    int li16 = lane & 15, quad = lane >> 4;

    for (int idx = t; idx < 192*15; idx += 512){
        int d = idx / 15, tokp = 49 + idx % 15;
        vT[d*64 + (tokp ^ ((d&7)<<3))] = tob(0.f);
    }

    // ---- phase Q: QKV for ALL heads, one long phase ----
    {
        int p = wv & 1, c = wv >> 1;
        int m0a = mt0(2*p), m0b = mt0(2*p+1);
        const bf16* hg = Hwin + (size_t)win*NN*CC;
        bf16x8v afa[6], afb[6];
        #pragma unroll
        for (int kc = 0; kc < 6; ++kc){
            afa[kc] = ldfrag(hg + (m0a+li16)*CC + kc*32 + quad*8);
            afb[kc] = ldfrag(hg + (m0b+li16)*CC + kc*32 + quad*8);
        }
        #pragma unroll 3
        for (int j = 0; j < 9; ++j){
            int nt = c + 4*j;
            int col = nt*16 + li16;
            f32x4 acc0 = {0.f,0.f,0.f,0.f}, acc1 = {0.f,0.f,0.f,0.f};
            #pragma unroll
            for (int kc = 0; kc < 6; ++kc){
                bf16x8v bfr = ldfrag(qkvw + (size_t)col*CC + kc*32 + quad*8);
                acc0 = __builtin_amdgcn_mfma_f32_16x16x32_bf16(afa[kc], bfr, acc0, 0, 0, 0);
                acc1 = __builtin_amdgcn_mfma_f32_16x16x32_bf16(afb[kc], bfr, acc1, 0, 0, 0);
            }
            float bias = tof(qkvb[col]);
            int m  = col / CC;
            int cm = col - m*CC;
            #pragma unroll
            for (int r = 0; r < 4; ++r){
                int rowA = m0a + quad*4 + r;
                int rowB = m0b + quad*4 + r;
                float v0 = acc0[r] + bias, v1 = acc1[r] + bias;
                if (m == 0){
                    qls[rowA*CC + (cm ^ ((rowA&7)<<3))] = tob(v0*SCALEQ);
                    qls[rowB*CC + (cm ^ ((rowB&7)<<3))] = tob(v1*SCALEQ);
                } else if (m == 1){
                    kls[rowA*CC + (cm ^ ((rowA&7)<<3))] = tob(v0);
                    kls[rowB*CC + (cm ^ ((rowB&7)<<3))] = tob(v1);
                } else {
                    vT[cm*64 + (rowA ^ ((cm&7)<<3))] = tob(v0);
                    vT[cm*64 + (rowB ^ ((cm&7)<<3))] = tob(v1);
                }
            }
        }
    }
    __syncthreads();   // #1

    unsigned int pk[3][8];
    #pragma unroll
    for (int j = 0; j < 3; ++j){
        int id = wv + 8*j;
        int mt = id & 3, h = id >> 2;
        int m0 = mt0(mt);
        int rowq = m0 + li16;
        bf16x8v afr = ldfrag(qls + rowq*CC + ((h*32 + quad*8) ^ ((rowq&7)<<3)));
        f32x4 s[4];
        #pragma unroll
        for (int nt = 0; nt < 4; ++nt){
            int rowk = nt*16 + li16;
            bf16x8v bfr = ldfrag(kls + rowk*CC + ((h*32 + quad*8) ^ ((rowk&7)<<3)));
            f32x4 z = {0.f,0.f,0.f,0.f};
            s[nt] = __builtin_amdgcn_mfma_f32_16x16x32_bf16(afr, bfr, z, 0, 0, 0);
        }
        #pragma unroll
        for (int nt = 0; nt < 4; ++nt){
            int jj = nt*16 + li16;
            int valid = (jj < NN);
            int jc = valid ? jj : 48;
            int yj = (jc*37) >> 8, xj = jc - 7*yj;
            int lj = 0;
            if (masked){
                int ayj = wh*WSS + yj, axj = ww*WSS + xj;
                lj = ((ayj<49)?0:(ayj<53)?1:2)*3 + ((axj<49)?0:(axj<53)?1:2);
            }
            #pragma unroll
            for (int r = 0; r < 4; ++r){
                int i = m0 + quad*4 + r;
                int yi = (i*37) >> 8, xi = i - 7*yi;
                int ridx = (yi - yj + 6)*13 + (xi - xj + 6);
                float v = s[nt][r] + tof(rpb[ridx*NHH + h]);
                if (masked){
                    int ayi = wh*WSS + yi, axi = ww*WSS + xi;
                    int li = ((ayi<49)?0:(ayi<53)?1:2)*3 + ((axi<49)?0:(axi<53)?1:2);
                    if (li != lj) v -= 100.f;
                }
                s[nt][r] = valid ? v : -1e30f;
            }
        }
        float mx[4], sm[4];
        #pragma unroll
        for (int r = 0; r < 4; ++r)
            mx[r] = fmaxf(fmaxf(s[0][r], s[1][r]), fmaxf(s[2][r], s[3][r]));
        #pragma unroll
        for (int st = 1; st < 16; st <<= 1){
            #pragma unroll
            for (int r = 0; r < 4; ++r) mx[r] = fmaxf(mx[r], __shfl_xor(mx[r], st));
        }
        #pragma unroll
        for (int nt = 0; nt < 4; ++nt){
            #pragma unroll
            for (int r = 0; r < 4; ++r) s[nt][r] = __expf(s[nt][r] - mx[r]);
        }
        #pragma unroll
        for (int r = 0; r < 4; ++r) sm[r] = (s[0][r]+s[1][r]) + (s[2][r]+s[3][r]);
        #pragma unroll
        for (int st = 1; st < 16; st <<= 1){
            #pragma unroll
            for (int r = 0; r < 4; ++r) sm[r] += __shfl_xor(sm[r], st);
        }
        #pragma unroll
        for (int r = 0; r < 4; ++r) sm[r] = 1.f / sm[r];
        #pragma unroll
        for (int nt = 0; nt < 4; ++nt){
            #pragma unroll
            for (int rr = 0; rr < 2; ++rr){
                unsigned int u0 = bfbits(s[nt][2*rr]   * sm[2*rr]);
                unsigned int u1 = bfbits(s[nt][2*rr+1] * sm[2*rr+1]);
                pk[j][nt*2+rr] = (u1 << 16) | u0;
            }
        }
    }
    __syncthreads();  // #2

    #pragma unroll
    for (int j = 0; j < 3; ++j){
        int id = wv + 8*j;
        int m0 = mt0(id & 3), h = id >> 2;
        #pragma unroll
        for (int nt = 0; nt < 4; ++nt){
            int jj = nt*16 + li16;
            #pragma unroll
            for (int rr = 0; rr < 2; ++rr){
                unsigned int u = pk[j][nt*2+rr];
                int tok0 = m0 + quad*4 + 2*rr;
                int tok1 = tok0 + 1;
                Pls[(h*NN + tok0)*64 + (jj ^ ((tok0&7)<<3))] = mkbf((unsigned short)(u & 0xffff));
                Pls[(h*NN + tok1)*64 + (jj ^ ((tok1&7)<<3))] = mkbf((unsigned short)(u >> 16));
            }
        }
    }
    __syncthreads();  // #3

    {
        int mt = wv & 3, nto = wv >> 2;
        int m0 = mt0(mt), n0 = nto*16;
        #pragma unroll
        for (int h = 0; h < NHH; ++h){
            f32x4 acc = {0.f,0.f,0.f,0.f};
            #pragma unroll
            for (int kc = 0; kc < 2; ++kc){
                int rowp = m0 + li16;
                bf16x8v afr = ldfrag(Pls + (h*NN + rowp)*64 + ((kc*32 + quad*8) ^ ((rowp&7)<<3)));
                int rowv = h*HDD + n0 + li16;
                bf16x8v bfr = ldfrag(vT + rowv*64 + ((kc*32 + quad*8) ^ ((rowv&7)<<3)));
                acc = __builtin_amdgcn_mfma_f32_16x16x32_bf16(afr, bfr, acc, 0, 0, 0);
            }
            #pragma unroll
            for (int r = 0; r < 4; ++r){
                int tok = m0 + quad*4 + r;
                AOut[(size_t)win*NN*CC + tok*CC + h*HDD + n0 + li16] = tob(acc[r]);
            }
        }
    }
}

// ---------- proj (MFMA) + window reverse + roll-by-WS bug + residual ----------
#define AS_STRIDE 200
template<typename XT>
__global__ __launch_bounds__(256) void k_proj_res(const bf16* __restrict__ AOut,
        const bf16* __restrict__ pw, const bf16* __restrict__ pb,
        XT* __restrict__ X, int shift){
    __shared__ bf16 as[32*AS_STRIDE];
    int t = threadIdx.x;
    int row0 = blockIdx.x * 32;
    for (int idx = t; idx < 32*CC; idx += 256){
        int r = idx / CC, c = idx % CC;
        as[r*AS_STRIDE + c] = AOut[(size_t)(row0 + r)*CC + c];
    }
    __syncthreads();
    int wv = t >> 6, lane = t & 63;
    int li16 = lane & 15, quad = lane >> 4;
    int roll = (shift > 0) ? WSS : 0;
    for (int nt = 0; nt < 3; ++nt){
        int n0 = wv*48 + nt*16;
        int col = n0 + li16;
        bf16x8v bfr[6];
        #pragma unroll
        for (int kc = 0; kc < 6; ++kc)
            bfr[kc] = ldfrag(pw + (size_t)col*CC + kc*32 + quad*8);
        float bias = tof(pb[col]);
        for (int mt = 0; mt < 2; ++mt){
            int m0 = mt*16;
            f32x4 acc = {0.f,0.f,0.f,0.f};
            #pragma unroll
            for (int kc = 0; kc < 6; ++kc){
                bf16x8v afr = ldfrag(as + (m0 + li16)*AS_STRIDE + kc*32 + quad*8);
                acc = __builtin_amdgcn_mfma_f32_16x16x32_bf16(afr, bfr[kc], acc, 0, 0, 0);
            }
            #pragma unroll
            for (int r = 0; r < 4; ++r){
                int grow = row0 + m0 + quad*4 + r;
                int b   = grow / (NWIN*NN);
                int rem = grow % (NWIN*NN);
                int win = rem / NN;
                int n   = rem % NN;
                int wh = win >> 3, ww = win & 7;
                int iy = n / WSS, ix = n % WSS;
                int y = (wh*WSS + iy + roll) % HH;
                int x = (ww*WSS + ix + roll) % WWI;
                size_t idx = ((size_t)(b*LL + y*WWI + x))*CC + col;
                xstore(&X[idx], xload(&X[idx]) + acc[r] + bias);
            }
        }
    }
}

// ---------- LN2 + FC1(MFMA) + GELU + FC2(MFMA) + residual, half-N 2-pass ----------
// LDS: xin 32x192 swz (12288B) + h1h 32x384 swz (24576B) + red (2304B) = 39168B
// -> 4 blocks/CU, VGPR capped 128 via launch_bounds(256,4)
template<typename XT>
__global__ __launch_bounds__(256, 4) void k_mlp(XT* __restrict__ X,
        const bf16* __restrict__ n2w, const bf16* __restrict__ n2b,
        const bf16* __restrict__ w1, const bf16* __restrict__ b1,
        const bf16* __restrict__ w2, const bf16* __restrict__ b2){
    __shared__ bf16  xin[32*192];
    __shared__ bf16  h1h[32*384];
    __shared__ float part[256], part2[256];
    __shared__ float stats[64];
    int t = threadIdx.x;
    size_t row0 = (size_t)blockIdx.x * 32;

    // ---- LN2: row r = t/8, cols s*24..s*24+23 held in registers ----
    float vals[24];
    int r8 = t >> 3, s8 = t & 7;
    {
        const XT* xr = X + (row0 + r8)*CC + s8*24;
        if constexpr (sizeof(XT) == 4){
            #pragma unroll
            for (int q = 0; q < 6; ++q){
                float4 f = *(const float4*)((const float*)xr + q*4);
                vals[q*4+0]=f.x; vals[q*4+1]=f.y; vals[q*4+2]=f.z; vals[q*4+3]=f.w;
            }
        } else {
            #pragma unroll
            for (int q = 0; q < 3; ++q){
                bf16x8v f = ldfrag((const bf16*)xr + q*8);
                #pragma unroll
                for (int e = 0; e < 8; ++e) vals[q*8+e] = tof(mkbf(__builtin_bit_cast(unsigned short, f[e])));
            }
        }
        float sm = 0.f, sm2 = 0.f;
        #pragma unroll
        for (int c = 0; c < 24; ++c){ sm += vals[c]; sm2 += vals[c]*vals[c]; }
        part[t] = sm; part2[t] = sm2;
    }
    __syncthreads();
    if (t < 32){
        float s = 0.f, s2 = 0.f;
        #pragma unroll
        for (int k = 0; k < 8; ++k){ s += part[t*8+k]; s2 += part2[t*8+k]; }
        float mu  = s * (1.f/CC);
        float var = s2 * (1.f/CC) - mu*mu;
        stats[t]      = mu;
        stats[32 + t] = rsqrtf(var + 1e-5f);
    }
    __syncthreads();
    {
        float mu = stats[r8], inv = stats[32+r8];
        #pragma unroll
        for (int c = 0; c < 24; ++c){
            int col = s8*24 + c;
            xin[r8*192 + (col ^ ((r8&7)<<3))] =
                tob((vals[c]-mu)*inv*tof(n2w[col]) + tof(n2b[col]));
        }
    }
    __syncthreads();

    int wv = t >> 6, lane = t & 63;
    int li16 = lane & 15, quad = lane >> 4;
    int sw = (li16 & 7) << 3;

    // hoisted FC1 A-fragments (rows m0+li16, m0 in {0,16})
    bf16x8v afr0[6], afr1[6];
    #pragma unroll
    for (int kc = 0; kc < 6; ++kc){
        afr0[kc] = ldfrag(xin + (0  + li16)*192 + ((kc*32 + quad*8) ^ sw));
        afr1[kc] = ldfrag(xin + (16 + li16)*192 + ((kc*32 + quad*8) ^ sw));
    }

    f32x4 acc2[3][2];
    #pragma unroll
    for (int nt = 0; nt < 3; ++nt){
        acc2[nt][0] = (f32x4){0.f,0.f,0.f,0.f};
        acc2[nt][1] = (f32x4){0.f,0.f,0.f,0.f};
    }

    #pragma unroll
    for (int half = 0; half < 2; ++half){
        // ---- FC1 half: 384 cols, 6 nt per wave ----
        #pragma unroll 2
        for (int nt6 = 0; nt6 < 6; ++nt6){
            int cl  = (wv*6 + nt6)*16 + li16;      // 0..383
            int col = half*384 + cl;
            bf16x8v bfr[6];
            #pragma unroll
            for (int kc = 0; kc < 6; ++kc)
                bfr[kc] = ldfrag(w1 + (size_t)col*CC + kc*32 + quad*8);
            float bb = tof(b1[col]);
            f32x4 acA = {0.f,0.f,0.f,0.f}, acB = {0.f,0.f,0.f,0.f};
            #pragma unroll
            for (int kc = 0; kc < 6; ++kc){
                acA = __builtin_amdgcn_mfma_f32_16x16x32_bf16(afr0[kc], bfr[kc], acA, 0, 0, 0);
                acB = __builtin_amdgcn_mfma_f32_16x16x32_bf16(afr1[kc], bfr[kc], acB, 0, 0, 0);
            }
            #pragma unroll
            for (int r = 0; r < 4; ++r){
                int rowA = quad*4 + r, rowB = 16 + quad*4 + r;
                h1h[rowA*384 + (cl ^ ((rowA&7)<<3))] = tob(fast_gelu(acA[r] + bb));
                h1h[rowB*384 + (cl ^ ((rowB&7)<<3))] = tob(fast_gelu(acB[r] + bb));
            }
        }
        __syncthreads();   // h1 half ready
        // ---- FC2 partial: K-half = 384 (12 kc), 3 nt per wave ----
        #pragma unroll 4
        for (int kc = 0; kc < 12; ++kc){
            int kg = half*12 + kc;
            bf16x8v a0 = ldfrag(h1h + (0  + li16)*384 + ((kc*32 + quad*8) ^ sw));
            bf16x8v a1 = ldfrag(h1h + (16 + li16)*384 + ((kc*32 + quad*8) ^ sw));
            #pragma unroll
            for (int nt = 0; nt < 3; ++nt){
                int col = wv*48 + nt*16 + li16;
                bf16x8v bfr = ldfrag(w2 + (size_t)col*768 + kg*32 + quad*8);
                acc2[nt][0] = __builtin_amdgcn_mfma_f32_16x16x32_bf16(a0, bfr, acc2[nt][0], 0, 0, 0);
                acc2[nt][1] = __builtin_amdgcn_mfma_f32_16x16x32_bf16(a1, bfr, acc2[nt][1], 0, 0, 0);
            }
        }
        __syncthreads();   // FC2 reads done before h1 overwrite
    }

    // ---- writeout + residual ----
    #pragma unroll
    for (int nt = 0; nt < 3; ++nt){
        int col = wv*48 + nt*16 + li16;
        float bias = tof(b2[col]);
        #pragma unroll
        for (int r = 0; r < 4; ++r){
            size_t i0 = (row0 + 0  + quad*4 + r)*CC + col;
            size_t i1 = (row0 + 16 + quad*4 + r)*CC + col;
            xstore(&X[i0], xload(&X[i0]) + acc2[nt][0][r] + bias);
            xstore(&X[i1], xload(&X[i1]) + acc2[nt][1][r] + bias);
        }
    }
}

// ---------- driver ----------
template<typename XT>
static void run_pipeline(const bf16* wb, const void* xin, int* flag,
                         XT* X, bf16* Hwin, bf16* AOut, void* out,
                         hipStream_t stream){
    k_convert_in<XT><<<(int)(TOT/256), 256, 0, stream>>>(xin, X, flag);
    for (int i = 0; i < 2; ++i){
        int shift = i ? (WSS/2) : 0;
        k_ln_part<XT><<<ROWS/4, 256, 0, stream>>>(X, wb+OFF_N1W + i*CC,
                wb+OFF_N1B + i*CC, Hwin, shift);
        k_attn<<<BB*NWIN, 512, 0, stream>>>(Hwin,
                wb+OFF_QKVW + (size_t)i*3*CC*CC, wb+OFF_QKVB + (size_t)i*3*CC,
                wb+OFF_RPB + (size_t)i*169*NHH, AOut, i);
        k_proj_res<XT><<<ROWS/32, 256, 0, stream>>>(AOut,
                wb+OFF_PROJW + (size_t)i*CC*CC, wb+OFF_PROJB + i*CC, X, shift);
        k_mlp<XT><<<ROWS/32, 256, 0, stream>>>(X,
                wb+OFF_N2W + i*CC, wb+OFF_N2B + i*CC,
                wb+OFF_F1W + (size_t)i*4*CC*CC, wb+OFF_F1B + (size_t)i*4*CC,
                wb+OFF_F2W + (size_t)i*CC*4*CC, wb+OFF_F2B + i*CC);
    }
    k_out<XT><<<(int)(TOT/256), 256, 0, stream>>>(X, out, flag);
}

extern "C" void kernel_launch(void* const* d_in, const int* in_sizes, int n_in,
                              void* d_out, int out_size, void* d_ws, size_t ws_size,
                              hipStream_t stream){
    char* p = (char*)d_ws;
    int*  flag = (int*)p;
    bf16* wb   = (bf16*)(p + 16);
    char* q    = p + 16 + (2u<<20);

    k_detect<<<1, 64, 0, stream>>>((const unsigned short*)d_in[1], flag);

    static const int widx[13] = {1,2,3,4,5,6,7,8,9,10,11,12,13};
    static const int woff[13] = {OFF_N1W,OFF_N1B,OFF_QKVW,OFF_QKVB,OFF_RPB,
                                 OFF_PROJW,OFF_PROJB,OFF_N2W,OFF_N2B,
                                 OFF_F1W,OFF_F1B,OFF_F2W,OFF_F2B};
    static const int wsz[13]  = {384,384,221184,1152,2028,73728,384,384,384,
                                 294912,1536,294912,384};
    for (int k = 0; k < 13; ++k)
        k_canon<<<(wsz[k]+255)/256, 256, 0, stream>>>(d_in[widx[k]], wb+woff[k],
                                                      wsz[k], flag);

    size_t needF32 = 16 + (2u<<20) + TOT*4 + TOT*2 + TOT*2;
    if (ws_size >= needF32){
        float* X   = (float*)q;       q += TOT*4;
        bf16* Hwin = (bf16*)q;        q += TOT*2;
        bf16* AOut = (bf16*)q;
        run_pipeline<float>(wb, d_in[0], flag, X, Hwin, AOut, d_out, stream);
    } else {
        bf16* X    = (bf16*)q;        q += TOT*2;
        bf16* Hwin = (bf16*)q;        q += TOT*2;
        bf16* AOut = (bf16*)q;
        run_pipeline<bf16>(wb, d_in[0], flag, X, Hwin, AOut, d_out, stream);
    }
}